// Round 2
// baseline (156.969 us; speedup 1.0000x reference)
//
#include <hip/hip_runtime.h>
#include <math.h>

typedef _Float16 h4  __attribute__((ext_vector_type(4)));
typedef _Float16 h8  __attribute__((ext_vector_type(8)));
typedef float    f4  __attribute__((ext_vector_type(4)));
typedef float    f32x4 __attribute__((ext_vector_type(4)));

#define W1_ELEMS (384*128)
#define W2_ELEMS (128*128)
#define LOG2E 1.44269504088896340736f

// Permute w1 rows to (kind, head, e)-major so that in the fused kernel,
// wave wv's three A-fragments are exactly head wv's Q, K, V channels.
// original row j: kind = j%3, c = j/3, h = c&7, e = c>>3
// permuted row  : jp = kind*128 + h*16 + e
__global__ void cvt_weights(const float* __restrict__ w1, const float* __restrict__ w2,
                            _Float16* __restrict__ w1h, _Float16* __restrict__ w2h) {
    int i = blockIdx.x * 256 + threadIdx.x;
    if (i < W1_ELEMS) {
        int j = i >> 7, k = i & 127;
        int c = j / 3;
        int kind = j - 3 * c;
        int jp = kind * 128 + (c & 7) * 16 + (c >> 3);
        w1h[jp * 128 + k] = (_Float16)w1[i];
    }
    if (i < W2_ELEMS) w2h[i] = (_Float16)w2[i];
}

// One block per (batch, window). 512 threads = 8 waves; wave wv owns head wv.
// LDS 74.5 KB -> 2 blocks/CU. 2 barriers (was 3): QKV is wave-private.
__global__ __launch_bounds__(512, 4)
void swin_fused(const float* __restrict__ x,
                const float* __restrict__ b1,
                const float* __restrict__ b2,
                const float* __restrict__ rel_bias,
                const _Float16* __restrict__ w1h,
                const _Float16* __restrict__ w2h,
                float* __restrict__ out)
{
    // xh: staged fp16 x rows (64 tok x 128 ch, stride 136 halves).
    __shared__ _Float16 xh[64*136];                 // 17408 B
    // Q (later O) and K: per-head [token][16 e] tiles, XOR-swizzled h4 groups.
    __shared__ _Float16 QO[8*64*16];                // 16384 B
    __shared__ _Float16 Kt[8*64*16];                // 16384 B
    __shared__ _Float16 Vt[8*16*68];                // [head][e][token], 17408 B
    __shared__ _Float16 bm[64*68];                  // [query i][key j] bias*log2e + mask

    const int tid  = threadIdx.x;
    const int lane = tid & 63;
    const int wv   = tid >> 6;       // wave id 0..7 == head
    const int quad = lane >> 4;      // 0..3
    const int l16  = lane & 15;
    // swizzle: element (t, e) lives at half-offset t*16 + ((e>>2)^s(t))*4 + (e&3),
    // s(t) = (t&3)^((t>>2)&3). All fragment accesses have t = 16*k + l16 -> s is lane-constant.
    const int s_lane = (l16 & 3) ^ ((l16 >> 2) & 3);
    const int swz    = (quad ^ s_lane) << 2;        // group==quad case, in halves

    const int blk = blockIdx.x;
    const int b   = blk >> 6;
    const int Hw  = (blk >> 3) & 7;
    const int Ww  = blk & 7;

    // ---- Phase 0a: gather shifted x rows -> fp16 LDS -------------------------
    {
        const int r0 = tid >> 5;        // 0..15
        const int c4 = tid & 31;        // float4 column
        #pragma unroll
        for (int it = 0; it < 4; ++it) {
            int t  = r0 + it*16;                      // token 0..63
            int gi = (Hw*8 + (t >> 3) + 4) & 63;      // shifted source row
            int gj = (Ww*8 + (t & 7) + 4) & 63;
            f32x4 v = *(const f32x4*)(x + ((size_t)b*4096 + gi*64 + gj)*128 + c4*4);
            h4 hv;
            hv[0] = (_Float16)v[0]; hv[1] = (_Float16)v[1];
            hv[2] = (_Float16)v[2]; hv[3] = (_Float16)v[3];
            *(h4*)(&xh[t*136 + c4*4]) = hv;
        }
    }
    // ---- Phase 0b: build bias+mask matrix bm[i][j] (transposed for h4 reads) -
    {
        const int rowm = (Hw == 7);
        const int colm = (Ww == 7);
        #pragma unroll
        for (int it = 0; it < 8; ++it) {
            int f = tid + it*512;       // 0..4095
            int j = f >> 6, i = f & 63; // j = key token, i = query token
            int hi = i >> 3, wi = i & 7, hj = j >> 3, wj = j & 7;
            float v = rel_bias[(hi - hj + 7)*15 + (wi - wj + 7)] * LOG2E;
            if (rowm && ((i ^ j) & 32)) v = -INFINITY;
            if (colm && ((i ^ j) & 4))  v = -INFINITY;
            bm[i*68 + j] = (_Float16)v;
        }
    }

    // bias gathers (overlap with barrier): j = 24*e + 3*h + kind, e = quad*4+r, h = wv
    float biasv[3][4];
    #pragma unroll
    for (int cc = 0; cc < 3; ++cc)
        #pragma unroll
        for (int r = 0; r < 4; ++r)
            biasv[cc][r] = b1[96*quad + 24*r + 3*wv + cc];

    __syncthreads();

    _Float16* Qh = &QO[wv*1024];
    _Float16* Kh = &Kt[wv*1024];

    // ---- Phase 1: QKV projection for head wv (A = permuted w1 rows) ----------
    {
        f4 acc[3][4];
        #pragma unroll
        for (int cc = 0; cc < 3; ++cc)
            #pragma unroll
            for (int tt = 0; tt < 4; ++tt)
                acc[cc][tt] = (f4){0.f,0.f,0.f,0.f};

        for (int kb = 0; kb < 4; ++kb) {
            h8 bfx[4];   // B operand: x tokens
            #pragma unroll
            for (int tt = 0; tt < 4; ++tt)
                bfx[tt] = *(const h8*)(&xh[(tt*16 + l16)*136 + kb*32 + quad*8]);
            #pragma unroll
            for (int cc = 0; cc < 3; ++cc) {
                // rows (cc*8+wv)*16 + l16 == kind cc, head wv, e = l16
                h8 afw = *(const h8*)(w1h + (size_t)((cc*8 + wv)*16 + l16)*128 + kb*32 + quad*8);
                #pragma unroll
                for (int tt = 0; tt < 4; ++tt)
                    acc[cc][tt] = __builtin_amdgcn_mfma_f32_16x16x32_f16(afw, bfx[tt], acc[cc][tt], 0, 0, 0);
            }
        }

        // epilogue: D row = e (quad*4+r), col = token. Vector h4 packs for Q,K.
        // Q scaled by 1/sqrt(16) * log2e (exp2-base softmax).
        const float qsc = 0.25f * LOG2E;
        #pragma unroll
        for (int tt = 0; tt < 4; ++tt) {
            int t = tt*16 + l16;
            h4 qv, kv;
            #pragma unroll
            for (int r = 0; r < 4; ++r) {
                qv[r] = (_Float16)((acc[0][tt][r] + biasv[0][r]) * qsc);
                kv[r] = (_Float16)( acc[1][tt][r] + biasv[1][r]);
            }
            *(h4*)(Qh + t*16 + swz) = qv;
            *(h4*)(Kh + t*16 + swz) = kv;
            #pragma unroll
            for (int r = 0; r < 4; ++r)
                Vt[(wv*16 + quad*4 + r)*68 + t] = (_Float16)(acc[2][tt][r] + biasv[2][r]);
        }
    }
    // NO barrier: head-wv QKV is produced and consumed by wave wv only.

    // ---- Phase 2: attention for head wv --------------------------------------
    {
        const _Float16* Vh = &Vt[wv*16*68];

        // K fragments (m = token j, k = e): one b64 per j-tile.
        h4 ak[4];
        #pragma unroll
        for (int mt = 0; mt < 4; ++mt)
            ak[mt] = *(const h4*)(Kh + (mt*16 + l16)*16 + swz);
        // V^T fragments (m = e = l16, k = token j): contiguous b64 reads.
        h4 av[4];
        #pragma unroll
        for (int kt = 0; kt < 4; ++kt)
            av[kt] = *(const h4*)(Vh + l16*68 + kt*16 + quad*4);

        for (int nt = 0; nt < 4; ++nt) {
            // Q^T B fragment (k = e, n = query i): one b64.
            h4 bq = *(const h4*)(Qh + (nt*16 + l16)*16 + swz);

            f4 T[4];
            #pragma unroll
            for (int mt = 0; mt < 4; ++mt) {
                f4 z = {0.f,0.f,0.f,0.f};
                T[mt] = __builtin_amdgcn_mfma_f32_16x16x16f16(ak[mt], bq, z, 0, 0, 0);
            }
            // bias+mask: h4 vector loads from transposed bm
            #pragma unroll
            for (int mt = 0; mt < 4; ++mt) {
                h4 bmv = *(const h4*)(&bm[(nt*16 + l16)*68 + mt*16 + quad*4]);
                #pragma unroll
                for (int r = 0; r < 4; ++r)
                    T[mt][r] += (float)bmv[r];
            }

            // softmax over keys j (exp2 base; log2e already folded in)
            float m = -INFINITY;
            #pragma unroll
            for (int mt = 0; mt < 4; ++mt)
                #pragma unroll
                for (int r = 0; r < 4; ++r) m = fmaxf(m, T[mt][r]);
            m = fmaxf(m, __shfl_xor(m, 16, 64));
            m = fmaxf(m, __shfl_xor(m, 32, 64));
            float s = 0.f;
            h4 P[4];
            #pragma unroll
            for (int mt = 0; mt < 4; ++mt)
                #pragma unroll
                for (int r = 0; r < 4; ++r) {
                    float p = __builtin_amdgcn_exp2f(T[mt][r] - m);
                    s += p;
                    P[mt][r] = (_Float16)p;
                }
            s += __shfl_xor(s, 16, 64);
            s += __shfl_xor(s, 32, 64);
            float rcp = 1.0f / s;

            // O^T tile: m = e, n = i, k = j
            f4 o = {0.f,0.f,0.f,0.f};
            #pragma unroll
            for (int kt = 0; kt < 4; ++kt)
                o = __builtin_amdgcn_mfma_f32_16x16x16f16(av[kt], P[kt], o, 0, 0, 0);
            h4 ov;
            #pragma unroll
            for (int r = 0; r < 4; ++r) ov[r] = (_Float16)(o[r] * rcp);
            // O overwrites this wave's (dead) Q rows: element (t = nt*16+l16, e = quad*4+r)
            *(h4*)(Qh + (nt*16 + l16)*16 + swz) = ov;
        }
    }
    __syncthreads();   // all heads' O must land before the output projection

    // ---- Phase 3: output projection (64x128, K=128), 1 N-tile per wave -------
    {
        const int o = wv*16 + l16;            // output channel
        const int g0 = (quad & 1) * 2;        // e-group pair within a head
        const int off0 = ((g0    ) ^ s_lane) << 2;
        const int off1 = ((g0 + 1) ^ s_lane) << 2;

        f4 acc3[4] = {{0.f,0.f,0.f,0.f},{0.f,0.f,0.f,0.f},{0.f,0.f,0.f,0.f},{0.f,0.f,0.f,0.f}};
        for (int kb = 0; kb < 4; ++kb) {
            h8 bf = *(const h8*)(w2h + (size_t)o*128 + kb*32 + quad*8);
            int hh = kb*2 + (quad >> 1);      // head of channels kb*32+quad*8 .. +7
            #pragma unroll
            for (int mt = 0; mt < 4; ++mt) {
                const _Float16* Ob = &QO[hh*1024 + (mt*16 + l16)*16];
                h4 a0 = *(const h4*)(Ob + off0);
                h4 a1 = *(const h4*)(Ob + off1);
                h8 af = { a0[0], a0[1], a0[2], a0[3], a1[0], a1[1], a1[2], a1[3] };
                acc3[mt] = __builtin_amdgcn_mfma_f32_16x16x32_f16(af, bf, acc3[mt], 0, 0, 0);
            }
        }
        float bias = b2[o];
        #pragma unroll
        for (int mt = 0; mt < 4; ++mt) {
            #pragma unroll
            for (int r = 0; r < 4; ++r) {
                int t  = mt*16 + quad*4 + r;
                int gi = Hw*8 + (t >> 3);
                int gj = Ww*8 + (t & 7);
                out[((size_t)b*4096 + gi*64 + gj)*128 + o] = acc3[mt][r] + bias;
            }
        }
    }
}

extern "C" void kernel_launch(void* const* d_in, const int* in_sizes, int n_in,
                              void* d_out, int out_size, void* d_ws, size_t ws_size,
                              hipStream_t stream) {
    (void)in_sizes; (void)n_in; (void)out_size; (void)ws_size;
    const float* x  = (const float*)d_in[0];
    const float* w1 = (const float*)d_in[1];
    const float* b1 = (const float*)d_in[2];
    const float* w2 = (const float*)d_in[3];
    const float* b2 = (const float*)d_in[4];
    const float* rb = (const float*)d_in[5];

    _Float16* w1h = (_Float16*)d_ws;
    _Float16* w2h = (_Float16*)((char*)d_ws + (size_t)W1_ELEMS * sizeof(_Float16));
    float* outp = (float*)d_out;

    cvt_weights<<<(W1_ELEMS + 255)/256, 256, 0, stream>>>(w1, w2, w1h, w2h);
    swin_fused<<<32*64, 512, 0, stream>>>(x, b1, b2, rb, w1h, w2h, outp);
}